// Round 8
// baseline (384.378 us; speedup 1.0000x reference)
//
#include <hip/hip_runtime.h>
#include <cstddef>

#define NPIX 1024   // H*W = 32*32

// ---------------------------------------------------------------------------
// Workspace layout (float-slot offsets). Peak 34,045,952 floats (136 MB).
// ---------------------------------------------------------------------------
static constexpr size_t WQKV_OFF  = 0;          //  98304 floats (768x256 bf16)
static constexpr size_t WPROJ_OFF = 98304;      //  65536 (256x512)
static constexpr size_t WINV_OFF  = 163840;     // 131072 (1024x256)
static constexpr size_t WPW_OFF   = 294912;     // 131072 (256x1024)
static constexpr size_t XT_OFF    = 425984;     // 2097152 (16x256x1024 bf16 blocked)
static constexpr size_t QKV_OFF   = 2523136;    // 6291456 (16x768x1024 bf16 [c][n])
static constexpr size_t DPW_OFF   = 8814592;    // 6291456
static constexpr size_t ATT_OFF   = 15106048;   // 4194304 (16x512x1024 bf16 blocked)
static constexpr size_t KVP_OFF   = 19300352;   // 270336 (256x1056 fp32, final kv)
static constexpr size_t T1_OFF    = 21463040;   // 4194304 (16x256x1024 fp32 [c][n])
static constexpr size_t T1T_OFF   = 25657344;   // 2097152 (16x32x1024x8 bf16 blocked)
static constexpr size_t H1T_OFF   = 425984;     // 8388608 (16x128x1024x8 bf16 blocked)
static constexpr size_t H2T_OFF   = 25657344;   // 8388608 (blocked; overwrites t1t after inv)

typedef __attribute__((ext_vector_type(8))) short bf16x8;
typedef __attribute__((ext_vector_type(8))) unsigned short u16x8;
typedef __attribute__((ext_vector_type(4))) unsigned short u16x4;
typedef __attribute__((ext_vector_type(4))) float f32x4;

__device__ inline unsigned short f2bf(float f) {
    union { float f; unsigned int u; } v; v.f = f;
    unsigned int u = v.u;
    u += 0x7FFFu + ((u >> 16) & 1u);        // round-to-nearest-even
    return (unsigned short)(u >> 16);
}
__device__ inline float bf2f(unsigned short u) {
    union { float f; unsigned int u; } v; v.u = ((unsigned int)u) << 16;
    return v.f;
}
__device__ inline u16x8 zero8() {
    u16x8 z = {0, 0, 0, 0, 0, 0, 0, 0};
    return z;
}

#define GLOAD_LDS16(gp, lp) __builtin_amdgcn_global_load_lds(                  \
    (const __attribute__((address_space(1))) unsigned int*)(const void*)(gp), \
    (__attribute__((address_space(3))) unsigned int*)(void*)(lp), 16, 0, 0)

// ---------------------------------------------------------------------------
// Weight convert: fp32 [O][K] -> blocked bf16 [K/8][O][8]
// ---------------------------------------------------------------------------
__global__ __launch_bounds__(256)
void wconv(const float* __restrict__ W, unsigned short* __restrict__ WB,
           const int O, const int K)
{
    const int idx = blockIdx.x * 256 + threadIdx.x;
    if (idx >= O * (K >> 3)) return;
    const int o = idx % O;
    const int koct = idx / O;
    u16x8 v;
#pragma unroll
    for (int j = 0; j < 8; j++) v[j] = f2bf(W[(size_t)o * K + koct * 8 + j]);
    *(u16x8*)(WB + ((size_t)koct * O + o) * 8) = v;
}

// ---------------------------------------------------------------------------
// Transpose: fp32 [b][C][1024] -> blocked bf16 [b][C/8][1024][8]
// ---------------------------------------------------------------------------
__global__ __launch_bounds__(256)
void xpose_f32_bf16(const float* __restrict__ X, unsigned short* __restrict__ XT,
                    const int C)
{
    __shared__ float tt[8][260];
    const int t = threadIdx.x;
    const int octs = C >> 3;
    const int strips = octs * 4;
    const int b = blockIdx.x / strips;
    const int rem = blockIdx.x - b * strips;
    const int coct = rem >> 2;
    const int n0 = (rem & 3) * 256;

    const int cc = t >> 5;
    const int c8 = (t & 31) * 8;
    const float* xp = X + ((size_t)b * C + coct * 8 + cc) * NPIX + n0 + c8;
    *(float4*)(&tt[cc][c8])     = *(const float4*)(xp);
    *(float4*)(&tt[cc][c8 + 4]) = *(const float4*)(xp + 4);
    __syncthreads();
    u16x8 v;
#pragma unroll
    for (int j = 0; j < 8; j++) v[j] = f2bf(tt[j][t]);
    *(u16x8*)(XT + (((size_t)b * octs + coct) * NPIX + n0 + t) * 8) = v;
}

// ---------------------------------------------------------------------------
// MFMA GEMM, blocked-bf16 operands:
//   X: [b][K/8][1024][8] bf16, W: [K/8][O][8] bf16;  Y = W·X (+ epilogue)
// Block tile BM x 128n, 4 waves (2x2). global_load_lds staging, double-buffer,
// m201-style swizzle folded into the global source slot.
// EPI: 0 plain, 1 BN+residual(+ACC), 2 bias+hswish.
// OMODE: 0 fp32 [c][n]; 1 bf16 [c][n] (LDS-transposed); 2 blocked bf16;
//        3 fp32 [c][n] + blocked bf16 (dual)
// ---------------------------------------------------------------------------
template<int BM, int EPI, bool ACC, int OMODE>
__global__ __launch_bounds__(256)
void gemm_blk(const unsigned short* __restrict__ X, const unsigned short* __restrict__ W,
              float* __restrict__ Y, unsigned short* __restrict__ YB,
              const int O, const int K,
              const float* __restrict__ res,
              const float* __restrict__ bng, const float* __restrict__ bnb,
              const float* __restrict__ bnm, const float* __restrict__ bnv,
              const float* __restrict__ bias)
{
    constexpr int MI = BM / 32;
    constexpr int SMEM_U16 = 2 * 64 * (BM + 128);
    constexpr int TSTR = (OMODE == 1) ? 136 : (BM + 8);
    __shared__ unsigned short smem[SMEM_U16];
    unsigned short* Asm = smem;                    // [2][BM][64]
    unsigned short* Bsm = smem + 2 * BM * 64;      // [2][128][64]
    unsigned short* T   = smem;                    // epilogue transpose (aliases)

    const int t    = threadIdx.x;
    const int lane = t & 63;
    const int w    = t >> 6;

    // XCD-bijective block swizzle (all grids are multiples of 8)
    const int gx  = gridDim.x;
    const int nwg = gx * gridDim.y;
    int bid = blockIdx.y * gx + blockIdx.x;
    bid = (bid & 7) * (nwg >> 3) + (bid >> 3);
    const int bx = bid % gx;
    const int by = bid / gx;

    const int o0 = bx * BM;
    const int b  = by >> 3;
    const int n0 = (by & 7) * 128;

    const int wo = (w >> 1) * (BM / 2);
    const int wn = (w & 1) * 64;

    f32x4 acc[MI][4];
#pragma unroll
    for (int i = 0; i < MI; i++)
#pragma unroll
        for (int j = 0; j < 4; j++) {
            f32x4 z = {0.f, 0.f, 0.f, 0.f};
            acc[i][j] = z;
        }

    const unsigned short* Xb = X + (size_t)b * K * NPIX;
    const int lr = lane >> 3;      // row-within-8 of this lane's 16B
    const int sp = lane & 7;       // physical 16B slot

    auto stage = [&](int d, int k0) {
        const int kb = k0 >> 3;
#pragma unroll
        for (int i = 0; i < 4; i++) {
            const int r0 = w * 32 + i * 8;
            const int r  = r0 + lr;
            const int sl = sp ^ (2 * ((r >> 2) & 1));
            const unsigned short* gp = Xb + (((size_t)(kb + sl)) * NPIX + n0 + r) * 8;
            GLOAD_LDS16(gp, Bsm + ((size_t)d * 128 + r0) * 64);
        }
#pragma unroll
        for (int i = 0; i < BM / 32; i++) {
            const int r0 = w * (BM / 4) + i * 8;
            const int r  = r0 + lr;
            const int sl = sp ^ (2 * ((r >> 2) & 1));
            const unsigned short* gp = W + (((size_t)(kb + sl)) * O + o0 + r) * 8;
            GLOAD_LDS16(gp, Asm + ((size_t)d * BM + r0) * 64);
        }
    };

    stage(0, 0);
    __syncthreads();

    const int l16 = lane & 15;
    const int lq  = lane >> 4;

    int cur = 0;
    for (int k0 = 0; k0 < K; k0 += 64) {
        if (k0 + 64 < K) stage(cur ^ 1, k0 + 64);
#pragma unroll
        for (int kk = 0; kk < 2; kk++) {
            bf16x8 afr[MI], bfr[4];
#pragma unroll
            for (int i = 0; i < MI; i++) {
                const int r = wo + i * 16 + l16;
                afr[i] = *(const bf16x8*)&Asm[((size_t)cur * BM + r) * 64 +
                          ((kk * 4 + lq) ^ (2 * ((r >> 2) & 1))) * 8];
            }
#pragma unroll
            for (int j = 0; j < 4; j++) {
                const int r = wn + j * 16 + l16;
                bfr[j] = *(const bf16x8*)&Bsm[((size_t)cur * 128 + r) * 64 +
                          ((kk * 4 + lq) ^ (2 * ((r >> 2) & 1))) * 8];
            }
#pragma unroll
            for (int i = 0; i < MI; i++)
#pragma unroll
                for (int j = 0; j < 4; j++)
                    acc[i][j] = __builtin_amdgcn_mfma_f32_16x16x32_bf16(
                        afr[i], bfr[j], acc[i][j], 0, 0, 0);
        }
        __syncthreads();
        cur ^= 1;
    }
    // after final barrier: As/Bs dead -> T may reuse smem.

    // epilogue. C/D: col = lane&15 (n), row = (lane>>4)*4 + reg (o)
    const int r0q = lq * 4;
    float scale[MI][4], shift[MI][4];
    if (EPI == 1) {
#pragma unroll
        for (int i = 0; i < MI; i++)
#pragma unroll
            for (int r = 0; r < 4; r++) {
                const int o = o0 + wo + i * 16 + r0q + r;
                const float inv = bng[o] / sqrtf(bnv[o] + 1e-5f);
                scale[i][r] = inv;
                shift[i][r] = bnb[o] - bnm[o] * inv;
            }
    } else if (EPI == 2) {
#pragma unroll
        for (int i = 0; i < MI; i++)
#pragma unroll
            for (int r = 0; r < 4; r++)
                shift[i][r] = bias[o0 + wo + i * 16 + r0q + r];
    }

#pragma unroll
    for (int i = 0; i < MI; i++) {
#pragma unroll
        for (int j = 0; j < 4; j++) {
            const int nn = n0 + wn + j * 16 + l16;
            const int nl = wn + j * 16 + l16;           // n within tile
            const int ob = wo + i * 16 + r0q;           // o base within tile
            const size_t base = ((size_t)b * O + o0 + ob) * NPIX + nn;
            u16x4 p4;
#pragma unroll
            for (int r = 0; r < 4; r++) {
                const size_t off = base + (size_t)r * NPIX;
                float v = acc[i][j][r];
                if (EPI == 1) {
                    v = v * scale[i][r] + shift[i][r] + res[off];
                } else if (EPI == 2) {
                    v += shift[i][r];
                    v = v * fminf(fmaxf(v + 3.f, 0.f), 6.f) * (1.f / 6.f);
                }
                if (OMODE == 0 || OMODE == 3) {
                    if (ACC) v += Y[off];
                    Y[off] = v;
                }
                if (OMODE == 1) {
                    T[(size_t)(ob + r) * TSTR + nl] = f2bf(v);
                } else if (OMODE >= 2) {
                    p4[r] = f2bf(v);
                }
            }
            if (OMODE >= 2)
                *(u16x4*)(T + (size_t)nl * TSTR + ob) = p4;
        }
    }

    if (OMODE >= 1) {
        __syncthreads();
        constexpr int CNT = BM / 16;
        if (OMODE == 1) {
#pragma unroll
            for (int k = 0; k < CNT; k++) {
                const int idx = t + k * 256;
                const int o   = idx >> 4;
                const int n8  = (idx & 15) * 8;
                const u16x8 v = *(const u16x8*)(T + (size_t)o * TSTR + n8);
                *(u16x8*)(YB + ((size_t)b * O + o0 + o) * NPIX + n0 + n8) = v;
            }
        } else {
#pragma unroll
            for (int k = 0; k < CNT; k++) {
                const int idx = t + k * 256;
                const int oo  = idx >> 7;
                const int nn  = idx & 127;
                const u16x8 v = *(const u16x8*)(T + (size_t)nn * TSTR + oo * 8);
                *(u16x8*)(YB + (((size_t)b * (O >> 3) + (o0 >> 3) + oo) * NPIX + n0 + nn) * 8) = v;
            }
        }
    }
}

// ---------------------------------------------------------------------------
// Depthwise 5x5 SAME, bf16 [c][n] in/out. fp32 LDS tile, 2 channels/block,
// register sliding window. Stride 44 padding.
// ---------------------------------------------------------------------------
__global__ __launch_bounds__(256)
void dwconv5x5_v3(const unsigned short* __restrict__ X, const float* __restrict__ Wd,
                  unsigned short* __restrict__ Y)
{
    __shared__ float tile[2 * 36 * 44];     // [ch][row 0..35][col 0..43], image+2 offset
    __shared__ float wl[64];                // [ch][25]
    const int t     = threadIdx.x;
    const int cpair = blockIdx.x % 384;
    const int b     = blockIdx.x / 384;
    const int cbase = cpair * 2;
    const unsigned short* xp = X + ((size_t)(b * 768 + cbase)) * NPIX;

    // zero whole tile (2*36*44 = 3168 floats = 792 float4)
#pragma unroll
    for (int k = 0; k < 4; k++) {
        const int i = t + k * 256;
        if (i < 792) {
            f32x4 z = {0.f, 0.f, 0.f, 0.f};
            *(f32x4*)(&tile[i * 4]) = z;
        }
    }
    if (t < 50) wl[(t / 25) * 32 + (t % 25)] = Wd[cbase * 25 + t];
    __syncthreads();

    const int ch = t >> 7;               // wave-uniform
    const int tm = t & 127;
    const int r  = tm >> 2;              // image row 0..31
    const int c8 = (tm & 3) * 8;         // image col base {0,8,16,24}

    // stage: 8 px -> fp32 interior [r+2][c8+2 .. +9]
    {
        const u16x8 v = *(const u16x8*)(xp + (size_t)ch * NPIX + r * 32 + c8);
        float* wp = &tile[ch * 1584 + (r + 2) * 44 + c8 + 2];
#pragma unroll
        for (int j = 0; j < 8; j += 2) {
            float2 f2v = make_float2(bf2f(v[j]), bf2f(v[j + 1]));
            *(float2*)(wp + j) = f2v;
        }
    }
    float wk[25];
#pragma unroll
    for (int i = 0; i < 25; i++) wk[i] = wl[ch * 32 + i];
    __syncthreads();

    float acc[8];
#pragma unroll
    for (int j = 0; j < 8; j++) acc[j] = 0.f;

#pragma unroll
    for (int ky = 0; ky < 5; ky++) {
        const float* rp = &tile[ch * 1584 + (r + ky) * 44 + c8];
        const f32x4 a = *(const f32x4*)(rp);
        const f32x4 bq = *(const f32x4*)(rp + 4);
        const f32x4 cq = *(const f32x4*)(rp + 8);
        const float in[12] = {a[0], a[1], a[2], a[3], bq[0], bq[1], bq[2], bq[3],
                              cq[0], cq[1], cq[2], cq[3]};
#pragma unroll
        for (int kx = 0; kx < 5; kx++) {
            const float wv = wk[ky * 5 + kx];
#pragma unroll
            for (int j = 0; j < 8; j++)
                acc[j] = fmaf(in[j + kx], wv, acc[j]);
        }
    }

    u16x8 o8;
#pragma unroll
    for (int j = 0; j < 8; j++) o8[j] = f2bf(acc[j]);
    *(u16x8*)(Y + ((size_t)(b * 768 + cbase + ch)) * NPIX + r * 32 + c8) = o8;
}

// ---------------------------------------------------------------------------
// Depthwise 3x3 + bias + hswish, blocked bf16 [coct][n][8] in -> blocked out.
// ---------------------------------------------------------------------------
__global__ __launch_bounds__(256)
void dwconv3x3_blk(const unsigned short* __restrict__ X, const float* __restrict__ Wd,
                   const float* __restrict__ bias, unsigned short* __restrict__ Y)
{
    __shared__ unsigned short tile[1024 * 8];
    __shared__ float wl[72];
    __shared__ float bb[8];
    const int t    = threadIdx.x;
    const int coct = blockIdx.x & 127;
    const int b    = blockIdx.x >> 7;
    const unsigned short* xp = X + ((size_t)(b * 128 + coct)) * NPIX * 8;
#pragma unroll
    for (int k = 0; k < 4; k++) {
        const int slot = t + k * 256;
        *(u16x8*)(&tile[slot * 8]) = *(const u16x8*)(xp + slot * 8);
    }
    if (t < 72) wl[t] = Wd[coct * 72 + t];
    if (t < 8)  bb[t] = bias[coct * 8 + t];
    __syncthreads();

    const int px0 = t * 4;
    const int h   = px0 >> 5;
    const int c0  = px0 & 31;

    float acc[8][4];
#pragma unroll
    for (int ch = 0; ch < 8; ch++)
#pragma unroll
        for (int j = 0; j < 4; j++) acc[ch][j] = bb[ch];

#pragma unroll
    for (int ky = 0; ky < 3; ky++) {
        const int rr = h + ky - 1;
        if (rr >= 0 && rr < 32) {
            u16x8 P[6];
#pragma unroll
            for (int m = 0; m < 6; m++) {
                const int col = c0 - 1 + m;
                const int colc = col < 0 ? 0 : (col > 31 ? 31 : col);
                u16x8 v = *(const u16x8*)(&tile[(rr * 32 + colc) * 8]);
                if (col < 0 || col > 31) v = zero8();
                P[m] = v;
            }
#pragma unroll
            for (int ch = 0; ch < 8; ch++) {
                float g[6];
#pragma unroll
                for (int m = 0; m < 6; m++) g[m] = bf2f(P[m][ch]);
#pragma unroll
                for (int j = 0; j < 4; j++)
#pragma unroll
                    for (int kx = 0; kx < 3; kx++)
                        acc[ch][j] = fmaf(g[j + kx], wl[ch * 9 + ky * 3 + kx], acc[ch][j]);
            }
        }
    }
    unsigned short* yp = Y + ((size_t)(b * 128 + coct)) * NPIX * 8 + (size_t)px0 * 8;
#pragma unroll
    for (int j = 0; j < 4; j++) {
        u16x8 o8;
#pragma unroll
        for (int ch = 0; ch < 8; ch++) {
            float v = acc[ch][j];
            v = v * fminf(fmaxf(v + 3.f, 0.f), 6.f) * (1.f / 6.f);
            o8[ch] = f2bf(v);
        }
        *(u16x8*)(yp + j * 8) = o8;
    }
}

// ---------------------------------------------------------------------------
// Grouped 32->32 1x1 (24 groups), in-place on bf16 [c][n] D.
// ---------------------------------------------------------------------------
__global__ __launch_bounds__(256)
void grouped_pw(unsigned short* __restrict__ D, const float* __restrict__ Wg)
{
    __shared__ float ws[1024];
    const int t     = threadIdx.x;
    const int blk   = blockIdx.x;          // (b*24+g)*4 + chunk
    const int chunk = blk & 3;
    const int bg    = blk >> 2;
    const int g     = bg % 24;
    const int b     = bg / 24;
    for (int i = t; i < 1024; i += 256) ws[i] = Wg[g * 1024 + i];
    __syncthreads();
    const int px = chunk * 256 + t;
    unsigned short* dp = D + ((size_t)(b * 768 + g * 32)) * NPIX + px;
    float in[32];
#pragma unroll
    for (int i = 0; i < 32; i++) in[i] = bf2f(dp[(size_t)i * NPIX]);
#pragma unroll
    for (int o = 0; o < 32; o++) {
        float s = 0.f;
#pragma unroll
        for (int i = 0; i < 32; i++) s = fmaf(ws[o * 32 + i], in[i], s);
        dp[(size_t)o * NPIX] = f2bf(s);
    }
}

// ---------------------------------------------------------------------------
// Attention kv via MFMA: one block per (b,h), 4 waves each over a 256-px
// n-chunk. Fragments loaded directly from global; final kv[33][32] to kvp.
// ---------------------------------------------------------------------------
__global__ __launch_bounds__(256)
void attn_kv_mfma(const unsigned short* __restrict__ qkv,
                  const unsigned short* __restrict__ dpw,
                  float* __restrict__ kvp)
{
    __shared__ float kvred[4][33 * 33];   // [wave][d*33+e], stride 33 pads banks
    const int t    = threadIdx.x;
    const int lane = t & 63;
    const int w    = t >> 6;
    const int bh   = blockIdx.x;
    const int b    = bh >> 4;
    const int h    = bh & 15;

    const unsigned short* base = (h < 8)
        ? qkv + ((size_t)(b * 768 + h * 96)) * NPIX
        : dpw + ((size_t)(b * 768 + (h - 8) * 96)) * NPIX;
    const unsigned short* kp = base + 32 * NPIX;
    const unsigned short* vp = base + 64 * NPIX;

    const int l16 = lane & 15;
    const int ko  = (lane >> 4) * 8;     // k-oct within the 32-wide step
    const int nb  = w * 256;

    f32x4 acc[3][2];
#pragma unroll
    for (int i = 0; i < 3; i++)
#pragma unroll
        for (int j = 0; j < 2; j++) {
            f32x4 z = {0.f, 0.f, 0.f, 0.f};
            acc[i][j] = z;
        }

    // constant ones-fragment: A-row 32 (d=32) is all-ones, rows 33..47 zero
    bf16x8 ones;
#pragma unroll
    for (int j = 0; j < 8; j++) ones[j] = (l16 == 0) ? (short)0x3F80 : (short)0;

#pragma unroll
    for (int s = 0; s < 8; s++) {
        const int n0 = nb + s * 32 + ko;
        const bf16x8 av0 = *(const bf16x8*)(vp + (size_t)l16 * NPIX + n0);
        const bf16x8 av1 = *(const bf16x8*)(vp + (size_t)(16 + l16) * NPIX + n0);
        const u16x8 k0 = *(const u16x8*)(kp + (size_t)l16 * NPIX + n0);
        const u16x8 k1 = *(const u16x8*)(kp + (size_t)(16 + l16) * NPIX + n0);
        bf16x8 bk0, bk1;
#pragma unroll
        for (int j = 0; j < 8; j++) {
            bk0[j] = (k0[j] & 0x8000u) ? (short)0 : (short)k0[j];   // relu (exact on bf16)
            bk1[j] = (k1[j] & 0x8000u) ? (short)0 : (short)k1[j];
        }
        acc[0][0] = __builtin_amdgcn_mfma_f32_16x16x32_bf16(av0,  bk0, acc[0][0], 0, 0, 0);
        acc[0][1] = __builtin_amdgcn_mfma_f32_16x16x32_bf16(av0,  bk1, acc[0][1], 0, 0, 0);
        acc[1][0] = __builtin_amdgcn_mfma_f32_16x16x32_bf16(av1,  bk0, acc[1][0], 0, 0, 0);
        acc[1][1] = __builtin_amdgcn_mfma_f32_16x16x32_bf16(av1,  bk1, acc[1][1], 0, 0, 0);
        acc[2][0] = __builtin_amdgcn_mfma_f32_16x16x32_bf16(ones, bk0, acc[2][0], 0, 0, 0);
        acc[2][1] = __builtin_amdgcn_mfma_f32_16x16x32_bf16(ones, bk1, acc[2][1], 0, 0, 0);
    }

    // write partials. C/D: row d = dt*16 + (lane>>4)*4 + r, col e = et*16 + l16
    const int rbase = (lane >> 4) * 4;
#pragma unroll
    for (int dt = 0; dt < 2; dt++)
#pragma unroll
        for (int et = 0; et < 2; et++)
#pragma unroll
            for (int r = 0; r < 4; r++)
                kvred[w][(dt * 16 + rbase + r) * 33 + et * 16 + l16] = acc[dt][et][r];
    if (rbase == 0) {               // d == 32 only (lanes 0..15, reg 0)
#pragma unroll
        for (int et = 0; et < 2; et++)
            kvred[w][32 * 33 + et * 16 + l16] = acc[2][et][0];
    }
    __syncthreads();

#pragma unroll
    for (int k = 0; k < 5; k++) {
        const int idx = t + k * 256;
        if (idx < 1056) {
            const int d = idx >> 5;
            const int e = idx & 31;
            const int a = d * 33 + e;
            kvp[(size_t)bh * 1056 + idx] =
                kvred[0][a] + kvred[1][a] + kvred[2][a] + kvred[3][a];
        }
    }
}

// ---------------------------------------------------------------------------
// Attention phase 2: load final kv, apply; OUT = blocked bf16
// att_t[b][64][1024][8]  (c = h*32 + db*8 + j)
// v2: 2 pixels/thread (q as float2[32]), kv read via ds_read_b128 (float4)
// -> LDS instruction count per pixel drops 8x vs scalar version.
// grid: bh*2 + half (512 blocks).
// ---------------------------------------------------------------------------
__global__ __launch_bounds__(256)
void attn_apply(const unsigned short* __restrict__ qkv,
                const unsigned short* __restrict__ dpw,
                const float* __restrict__ kvp, unsigned short* __restrict__ att)
{
    __shared__ float kvs[1056];
    const int t    = threadIdx.x;
    const int blk  = blockIdx.x;          // bh*2 + half
    const int half = blk & 1;
    const int bh   = blk >> 1;
    const int b    = bh >> 4;
    const int h    = bh & 15;
    {
        const int i = t;                   // 264 float4 = 1056 floats
        if (i < 264)
            *(f32x4*)(&kvs[i * 4]) = *(const f32x4*)(kvp + (size_t)bh * 1056 + i * 4);
        const int i2 = t + 256;
        if (i2 < 264)
            *(f32x4*)(&kvs[i2 * 4]) = *(const f32x4*)(kvp + (size_t)bh * 1056 + i2 * 4);
    }
    __syncthreads();
    const unsigned short* qp = (h < 8)
        ? qkv + ((size_t)(b * 768 + h * 96)) * NPIX
        : dpw + ((size_t)(b * 768 + (h - 8) * 96)) * NPIX;
    const int n = half * 512 + t * 2;     // 2 consecutive pixels

    float2 q[32];
#pragma unroll
    for (int e = 0; e < 32; e++) {
        const unsigned int u = *(const unsigned int*)(qp + (size_t)e * NPIX + n);
        q[e].x = fmaxf(bf2f((unsigned short)(u & 0xFFFFu)), 0.f);
        q[e].y = fmaxf(bf2f((unsigned short)(u >> 16)), 0.f);
    }

    float2 den = make_float2(0.f, 0.f);
#pragma unroll
    for (int eq = 0; eq < 8; eq++) {
        const f32x4 kvv = *(const f32x4*)(&kvs[1024 + eq * 4]);
#pragma unroll
        for (int j = 0; j < 4; j++) {
            den.x = fmaf(kvv[j], q[eq * 4 + j].x, den.x);
            den.y = fmaf(kvv[j], q[eq * 4 + j].y, den.y);
        }
    }
    const float invx = 1.f / (den.x + 1e-15f);
    const float invy = 1.f / (den.y + 1e-15f);

#pragma unroll
    for (int db = 0; db < 4; db++) {
        u16x8 o0, o1;
#pragma unroll
        for (int jj = 0; jj < 8; jj++) {
            const int d = db * 8 + jj;
            float ax = 0.f, ay = 0.f;
#pragma unroll
            for (int eq = 0; eq < 8; eq++) {
                const f32x4 kvv = *(const f32x4*)(&kvs[d * 32 + eq * 4]);
#pragma unroll
                for (int j = 0; j < 4; j++) {
                    ax = fmaf(kvv[j], q[eq * 4 + j].x, ax);
                    ay = fmaf(kvv[j], q[eq * 4 + j].y, ay);
                }
            }
            o0[jj] = f2bf(ax * invx);
            o1[jj] = f2bf(ay * invy);
        }
        unsigned short* op = att + (((size_t)(b * 64 + h * 4 + db)) * NPIX + n) * 8;
        *(u16x8*)(op)     = o0;
        *(u16x8*)(op + 8) = o1;
    }
}

// ---------------------------------------------------------------------------
extern "C" void kernel_launch(void* const* d_in, const int* in_sizes, int n_in,
                              void* d_out, int out_size, void* d_ws, size_t ws_size,
                              hipStream_t stream)
{
    (void)in_sizes; (void)n_in; (void)out_size; (void)ws_size;

    const float* x      = (const float*)d_in[0];
    const float* y      = (const float*)d_in[1];
    const float* qkv_w  = (const float*)d_in[2];
    const float* dw5_w  = (const float*)d_in[3];
    const float* pwg_w  = (const float*)d_in[4];
    const float* proj_w = (const float*)d_in[5];
    const float* proj_g = (const float*)d_in[6];
    const float* proj_b = (const float*)d_in[7];
    const float* proj_m = (const float*)d_in[8];
    const float* proj_v = (const float*)d_in[9];
    const float* inv_w  = (const float*)d_in[10];
    const float* inv_b  = (const float*)d_in[11];
    const float* dwc_w  = (const float*)d_in[12];
    const float* dwc_b  = (const float*)d_in[13];
    const float* pw_w   = (const float*)d_in[14];
    const float* pw_g   = (const float*)d_in[15];
    const float* pw_b   = (const float*)d_in[16];
    const float* pw_m   = (const float*)d_in[17];
    const float* pw_v   = (const float*)d_in[18];

    float* ws = (float*)d_ws;
    unsigned short* wqkv_b  = (unsigned short*)(ws + WQKV_OFF);
    unsigned short* wproj_b = (unsigned short*)(ws + WPROJ_OFF);
    unsigned short* winv_b  = (unsigned short*)(ws + WINV_OFF);
    unsigned short* wpw_b   = (unsigned short*)(ws + WPW_OFF);
    unsigned short* wxt     = (unsigned short*)(ws + XT_OFF);
    unsigned short* wqkv    = (unsigned short*)(ws + QKV_OFF);
    unsigned short* wdpw    = (unsigned short*)(ws + DPW_OFF);
    unsigned short* watt    = (unsigned short*)(ws + ATT_OFF);
    float*          wkvp    = ws + KVP_OFF;
    float*          wt1     = ws + T1_OFF;
    unsigned short* wt1t    = (unsigned short*)(ws + T1T_OFF);
    unsigned short* wh1t    = (unsigned short*)(ws + H1T_OFF);
    unsigned short* wh2t    = (unsigned short*)(ws + H2T_OFF);
    float* out = (float*)d_out;

    // weights -> blocked bf16 (once per launch)
    wconv<<<dim3(96),  256, 0, stream>>>(qkv_w,  wqkv_b,  768, 256);
    wconv<<<dim3(64),  256, 0, stream>>>(proj_w, wproj_b, 256, 512);
    wconv<<<dim3(128), 256, 0, stream>>>(inv_w,  winv_b,  1024, 256);
    wconv<<<dim3(128), 256, 0, stream>>>(pw_w,   wpw_b,   256, 1024);

    for (int blk = 0; blk < 2; blk++) {
        const float* t = (blk == 0) ? x : y;

        // --- lite_mla ---
        xpose_f32_bf16<<<dim3(2048), 256, 0, stream>>>(t, wxt, 256);
        gemm_blk<128, 0, false, 1><<<dim3(6, 128), 256, 0, stream>>>(
            wxt, wqkv_b, nullptr, wqkv, 768, 256,
            nullptr, nullptr, nullptr, nullptr, nullptr, nullptr);
        dwconv5x5_v3<<<dim3(6144), 256, 0, stream>>>(wqkv, dw5_w, wdpw);
        grouped_pw<<<dim3(1536), 256, 0, stream>>>(wdpw, pwg_w);
        attn_kv_mfma<<<dim3(256), 256, 0, stream>>>(wqkv, wdpw, wkvp);
        attn_apply<<<dim3(512), 256, 0, stream>>>(wqkv, wdpw, wkvp, watt);
        gemm_blk<64, 1, false, 3><<<dim3(4, 128), 256, 0, stream>>>(
            watt, wproj_b, wt1, wt1t, 256, 512,
            t, proj_g, proj_b, proj_m, proj_v, nullptr);

        // --- mbconv ---
        gemm_blk<128, 2, false, 2><<<dim3(8, 128), 256, 0, stream>>>(
            wt1t, winv_b, nullptr, wh1t, 1024, 256,
            nullptr, nullptr, nullptr, nullptr, nullptr, inv_b);
        dwconv3x3_blk<<<dim3(2048), 256, 0, stream>>>(wh1t, dwc_w, dwc_b, wh2t);
        if (blk == 0) {
            gemm_blk<64, 1, false, 0><<<dim3(4, 128), 256, 0, stream>>>(
                wh2t, wpw_b, out, nullptr, 256, 1024,
                wt1, pw_g, pw_b, pw_m, pw_v, nullptr);
        } else {
            gemm_blk<64, 1, true, 0><<<dim3(4, 128), 256, 0, stream>>>(
                wh2t, wpw_b, out, nullptr, 256, 1024,
                wt1, pw_g, pw_b, pw_m, pw_v, nullptr);
        }
    }
}

// Round 10
// 367.255 us; speedup vs baseline: 1.0466x; 1.0466x over previous
//
#include <hip/hip_runtime.h>
#include <cstddef>

#define NPIX 1024   // H*W = 32*32

// ---------------------------------------------------------------------------
// Workspace layout (float-slot offsets). Peak 34,045,952 floats (136 MB).
// ---------------------------------------------------------------------------
static constexpr size_t WQKV_OFF  = 0;          //  98304 floats (768x256 bf16)
static constexpr size_t WPROJ_OFF = 98304;      //  65536 (256x512)
static constexpr size_t WINV_OFF  = 163840;     // 131072 (1024x256)
static constexpr size_t WPW_OFF   = 294912;     // 131072 (256x1024)
static constexpr size_t XT_OFF    = 425984;     // 2097152 (16x256x1024 bf16 blocked)
static constexpr size_t QKV_OFF   = 2523136;    // 6291456 (16x768x1024 bf16 [c][n])
static constexpr size_t DPW_OFF   = 8814592;    // 6291456
static constexpr size_t ATT_OFF   = 15106048;   // 4194304 (16x512x1024 bf16 blocked)
static constexpr size_t KVP_OFF   = 19300352;   // 270336 (256x1056 fp32, final kv)
static constexpr size_t T1_OFF    = 21463040;   // 4194304 (16x256x1024 fp32 [c][n])
static constexpr size_t T1T_OFF   = 25657344;   // 2097152 (16x32x1024x8 bf16 blocked)
static constexpr size_t H1T_OFF   = 425984;     // 8388608 (16x128x1024x8 bf16 blocked)
static constexpr size_t H2T_OFF   = 25657344;   // 8388608 (blocked; overwrites t1t after inv)

typedef __attribute__((ext_vector_type(8))) short bf16x8;
typedef __attribute__((ext_vector_type(8))) unsigned short u16x8;
typedef __attribute__((ext_vector_type(4))) unsigned short u16x4;
typedef __attribute__((ext_vector_type(4))) float f32x4;

__device__ inline unsigned short f2bf(float f) {
    union { float f; unsigned int u; } v; v.f = f;
    unsigned int u = v.u;
    u += 0x7FFFu + ((u >> 16) & 1u);        // round-to-nearest-even
    return (unsigned short)(u >> 16);
}
__device__ inline float bf2f(unsigned short u) {
    union { float f; unsigned int u; } v; v.u = ((unsigned int)u) << 16;
    return v.f;
}
__device__ inline u16x8 zero8() {
    u16x8 z = {0, 0, 0, 0, 0, 0, 0, 0};
    return z;
}

#define GLOAD_LDS16(gp, lp) __builtin_amdgcn_global_load_lds(                  \
    (const __attribute__((address_space(1))) unsigned int*)(const void*)(gp), \
    (__attribute__((address_space(3))) unsigned int*)(void*)(lp), 16, 0, 0)

// ---------------------------------------------------------------------------
// Weight convert: fp32 [O][K] -> blocked bf16 [K/8][O][8]
// ---------------------------------------------------------------------------
__global__ __launch_bounds__(256)
void wconv(const float* __restrict__ W, unsigned short* __restrict__ WB,
           const int O, const int K)
{
    const int idx = blockIdx.x * 256 + threadIdx.x;
    if (idx >= O * (K >> 3)) return;
    const int o = idx % O;
    const int koct = idx / O;
    u16x8 v;
#pragma unroll
    for (int j = 0; j < 8; j++) v[j] = f2bf(W[(size_t)o * K + koct * 8 + j]);
    *(u16x8*)(WB + ((size_t)koct * O + o) * 8) = v;
}

// ---------------------------------------------------------------------------
// Transpose: fp32 [b][C][1024] -> blocked bf16 [b][C/8][1024][8]
// ---------------------------------------------------------------------------
__global__ __launch_bounds__(256)
void xpose_f32_bf16(const float* __restrict__ X, unsigned short* __restrict__ XT,
                    const int C)
{
    __shared__ float tt[8][260];
    const int t = threadIdx.x;
    const int octs = C >> 3;
    const int strips = octs * 4;
    const int b = blockIdx.x / strips;
    const int rem = blockIdx.x - b * strips;
    const int coct = rem >> 2;
    const int n0 = (rem & 3) * 256;

    const int cc = t >> 5;
    const int c8 = (t & 31) * 8;
    const float* xp = X + ((size_t)b * C + coct * 8 + cc) * NPIX + n0 + c8;
    *(float4*)(&tt[cc][c8])     = *(const float4*)(xp);
    *(float4*)(&tt[cc][c8 + 4]) = *(const float4*)(xp + 4);
    __syncthreads();
    u16x8 v;
#pragma unroll
    for (int j = 0; j < 8; j++) v[j] = f2bf(tt[j][t]);
    *(u16x8*)(XT + (((size_t)b * octs + coct) * NPIX + n0 + t) * 8) = v;
}

// ---------------------------------------------------------------------------
// MFMA GEMM, blocked-bf16 operands:
//   X: [b][K/8][1024][8] bf16, W: [K/8][O][8] bf16;  Y = W·X (+ epilogue)
// Block tile BM x 128n, 4 waves (2x2). global_load_lds staging, double-buffer.
// Swizzle: slot ^= (row & 7) (full 3-bit), folded into the GLOBAL source
// k-oct on stage and applied on ds_read -> 2-way (free) frag reads.
// EPI: 0 plain, 1 BN+residual(+ACC), 2 bias+hswish.
// OMODE: 0 fp32 [c][n]; 1 bf16 [c][n] (LDS-transposed); 2 blocked bf16;
//        3 fp32 [c][n] + blocked bf16 (dual)
// ---------------------------------------------------------------------------
template<int BM, int EPI, bool ACC, int OMODE>
__global__ __launch_bounds__(256)
void gemm_blk(const unsigned short* __restrict__ X, const unsigned short* __restrict__ W,
              float* __restrict__ Y, unsigned short* __restrict__ YB,
              const int O, const int K,
              const float* __restrict__ res,
              const float* __restrict__ bng, const float* __restrict__ bnb,
              const float* __restrict__ bnm, const float* __restrict__ bnv,
              const float* __restrict__ bias)
{
    constexpr int MI = BM / 32;
    constexpr int SMEM_U16 = 2 * 64 * (BM + 128);
    constexpr int TSTR = (OMODE == 1) ? 136 : (BM + 8);
    __shared__ unsigned short smem[SMEM_U16];
    unsigned short* Asm = smem;                    // [2][BM][64]
    unsigned short* Bsm = smem + 2 * BM * 64;      // [2][128][64]
    unsigned short* T   = smem;                    // epilogue transpose (aliases)

    const int t    = threadIdx.x;
    const int lane = t & 63;
    const int w    = t >> 6;

    // XCD-bijective block swizzle (all grids are multiples of 8)
    const int gx  = gridDim.x;
    const int nwg = gx * gridDim.y;
    int bid = blockIdx.y * gx + blockIdx.x;
    bid = (bid & 7) * (nwg >> 3) + (bid >> 3);
    const int bx = bid % gx;
    const int by = bid / gx;

    const int o0 = bx * BM;
    const int b  = by >> 3;
    const int n0 = (by & 7) * 128;

    const int wo = (w >> 1) * (BM / 2);
    const int wn = (w & 1) * 64;

    f32x4 acc[MI][4];
#pragma unroll
    for (int i = 0; i < MI; i++)
#pragma unroll
        for (int j = 0; j < 4; j++) {
            f32x4 z = {0.f, 0.f, 0.f, 0.f};
            acc[i][j] = z;
        }

    const unsigned short* Xb = X + (size_t)b * K * NPIX;
    const int lr = lane >> 3;      // row-within-8 of this lane's 16B
    const int sp = lane & 7;       // physical 16B slot

    auto stage = [&](int d, int k0) {
        const int kb = k0 >> 3;
#pragma unroll
        for (int i = 0; i < 4; i++) {
            const int r0 = w * 32 + i * 8;
            const int r  = r0 + lr;
            const int sl = sp ^ (r & 7);
            const unsigned short* gp = Xb + (((size_t)(kb + sl)) * NPIX + n0 + r) * 8;
            GLOAD_LDS16(gp, Bsm + ((size_t)d * 128 + r0) * 64);
        }
#pragma unroll
        for (int i = 0; i < BM / 32; i++) {
            const int r0 = w * (BM / 4) + i * 8;
            const int r  = r0 + lr;
            const int sl = sp ^ (r & 7);
            const unsigned short* gp = W + (((size_t)(kb + sl)) * O + o0 + r) * 8;
            GLOAD_LDS16(gp, Asm + ((size_t)d * BM + r0) * 64);
        }
    };

    stage(0, 0);
    __syncthreads();

    const int l16 = lane & 15;
    const int lq  = lane >> 4;

    int cur = 0;
    for (int k0 = 0; k0 < K; k0 += 64) {
        if (k0 + 64 < K) stage(cur ^ 1, k0 + 64);
#pragma unroll
        for (int kk = 0; kk < 2; kk++) {
            bf16x8 afr[MI], bfr[4];
#pragma unroll
            for (int i = 0; i < MI; i++) {
                const int r = wo + i * 16 + l16;
                afr[i] = *(const bf16x8*)&Asm[((size_t)cur * BM + r) * 64 +
                          ((kk * 4 + lq) ^ (r & 7)) * 8];
            }
#pragma unroll
            for (int j = 0; j < 4; j++) {
                const int r = wn + j * 16 + l16;
                bfr[j] = *(const bf16x8*)&Bsm[((size_t)cur * 128 + r) * 64 +
                          ((kk * 4 + lq) ^ (r & 7)) * 8];
            }
#pragma unroll
            for (int i = 0; i < MI; i++)
#pragma unroll
                for (int j = 0; j < 4; j++)
                    acc[i][j] = __builtin_amdgcn_mfma_f32_16x16x32_bf16(
                        afr[i], bfr[j], acc[i][j], 0, 0, 0);
        }
        __syncthreads();
        cur ^= 1;
    }
    // after final barrier: As/Bs dead -> T may reuse smem.

    // epilogue. C/D: col = lane&15 (n), row = (lane>>4)*4 + reg (o)
    const int r0q = lq * 4;
    float scale[MI][4], shift[MI][4];
    if (EPI == 1) {
#pragma unroll
        for (int i = 0; i < MI; i++)
#pragma unroll
            for (int r = 0; r < 4; r++) {
                const int o = o0 + wo + i * 16 + r0q + r;
                const float inv = bng[o] / sqrtf(bnv[o] + 1e-5f);
                scale[i][r] = inv;
                shift[i][r] = bnb[o] - bnm[o] * inv;
            }
    } else if (EPI == 2) {
#pragma unroll
        for (int i = 0; i < MI; i++)
#pragma unroll
            for (int r = 0; r < 4; r++)
                shift[i][r] = bias[o0 + wo + i * 16 + r0q + r];
    }

#pragma unroll
    for (int i = 0; i < MI; i++) {
#pragma unroll
        for (int j = 0; j < 4; j++) {
            const int nn = n0 + wn + j * 16 + l16;
            const int nl = wn + j * 16 + l16;           // n within tile
            const int ob = wo + i * 16 + r0q;           // o base within tile
            const size_t base = ((size_t)b * O + o0 + ob) * NPIX + nn;
            u16x4 p4;
#pragma unroll
            for (int r = 0; r < 4; r++) {
                const size_t off = base + (size_t)r * NPIX;
                float v = acc[i][j][r];
                if (EPI == 1) {
                    v = v * scale[i][r] + shift[i][r] + res[off];
                } else if (EPI == 2) {
                    v += shift[i][r];
                    v = v * fminf(fmaxf(v + 3.f, 0.f), 6.f) * (1.f / 6.f);
                }
                if (OMODE == 0 || OMODE == 3) {
                    if (ACC) v += Y[off];
                    Y[off] = v;
                }
                if (OMODE == 1) {
                    T[(size_t)(ob + r) * TSTR + nl] = f2bf(v);
                } else if (OMODE >= 2) {
                    p4[r] = f2bf(v);
                }
            }
            if (OMODE >= 2)
                *(u16x4*)(T + (size_t)nl * TSTR + ob) = p4;
        }
    }

    if (OMODE >= 1) {
        __syncthreads();
        constexpr int CNT = BM / 16;
        if (OMODE == 1) {
#pragma unroll
            for (int k = 0; k < CNT; k++) {
                const int idx = t + k * 256;
                const int o   = idx >> 4;
                const int n8  = (idx & 15) * 8;
                const u16x8 v = *(const u16x8*)(T + (size_t)o * TSTR + n8);
                *(u16x8*)(YB + ((size_t)b * O + o0 + o) * NPIX + n0 + n8) = v;
            }
        } else {
#pragma unroll
            for (int k = 0; k < CNT; k++) {
                const int idx = t + k * 256;
                const int oo  = idx >> 7;
                const int nn  = idx & 127;
                const u16x8 v = *(const u16x8*)(T + (size_t)nn * TSTR + oo * 8);
                *(u16x8*)(YB + (((size_t)b * (O >> 3) + (o0 >> 3) + oo) * NPIX + n0 + nn) * 8) = v;
            }
        }
    }
}

// ---------------------------------------------------------------------------
// Depthwise 5x5 SAME, bf16 [c][n] in/out. fp32 LDS tile, 2 channels/block,
// register sliding window. Stride 44 padding.
// ---------------------------------------------------------------------------
__global__ __launch_bounds__(256)
void dwconv5x5_v3(const unsigned short* __restrict__ X, const float* __restrict__ Wd,
                  unsigned short* __restrict__ Y)
{
    __shared__ float tile[2 * 36 * 44];     // [ch][row 0..35][col 0..43], image+2 offset
    __shared__ float wl[64];                // [ch][25]
    const int t     = threadIdx.x;
    const int cpair = blockIdx.x % 384;
    const int b     = blockIdx.x / 384;
    const int cbase = cpair * 2;
    const unsigned short* xp = X + ((size_t)(b * 768 + cbase)) * NPIX;

    // zero whole tile (2*36*44 = 3168 floats = 792 float4)
#pragma unroll
    for (int k = 0; k < 4; k++) {
        const int i = t + k * 256;
        if (i < 792) {
            f32x4 z = {0.f, 0.f, 0.f, 0.f};
            *(f32x4*)(&tile[i * 4]) = z;
        }
    }
    if (t < 50) wl[(t / 25) * 32 + (t % 25)] = Wd[cbase * 25 + t];
    __syncthreads();

    const int ch = t >> 7;               // wave-uniform
    const int tm = t & 127;
    const int r  = tm >> 2;              // image row 0..31
    const int c8 = (tm & 3) * 8;         // image col base {0,8,16,24}

    // stage: 8 px -> fp32 interior [r+2][c8+2 .. +9]
    {
        const u16x8 v = *(const u16x8*)(xp + (size_t)ch * NPIX + r * 32 + c8);
        float* wp = &tile[ch * 1584 + (r + 2) * 44 + c8 + 2];
#pragma unroll
        for (int j = 0; j < 8; j += 2) {
            float2 f2v = make_float2(bf2f(v[j]), bf2f(v[j + 1]));
            *(float2*)(wp + j) = f2v;
        }
    }
    float wk[25];
#pragma unroll
    for (int i = 0; i < 25; i++) wk[i] = wl[ch * 32 + i];
    __syncthreads();

    float acc[8];
#pragma unroll
    for (int j = 0; j < 8; j++) acc[j] = 0.f;

#pragma unroll
    for (int ky = 0; ky < 5; ky++) {
        const float* rp = &tile[ch * 1584 + (r + ky) * 44 + c8];
        const f32x4 a = *(const f32x4*)(rp);
        const f32x4 bq = *(const f32x4*)(rp + 4);
        const f32x4 cq = *(const f32x4*)(rp + 8);
        const float in[12] = {a[0], a[1], a[2], a[3], bq[0], bq[1], bq[2], bq[3],
                              cq[0], cq[1], cq[2], cq[3]};
#pragma unroll
        for (int kx = 0; kx < 5; kx++) {
            const float wv = wk[ky * 5 + kx];
#pragma unroll
            for (int j = 0; j < 8; j++)
                acc[j] = fmaf(in[j + kx], wv, acc[j]);
        }
    }

    u16x8 o8;
#pragma unroll
    for (int j = 0; j < 8; j++) o8[j] = f2bf(acc[j]);
    *(u16x8*)(Y + ((size_t)(b * 768 + cbase + ch)) * NPIX + r * 32 + c8) = o8;
}

// ---------------------------------------------------------------------------
// Depthwise 3x3 + bias + hswish, blocked bf16 [coct][n][8] in -> blocked out.
// ---------------------------------------------------------------------------
__global__ __launch_bounds__(256)
void dwconv3x3_blk(const unsigned short* __restrict__ X, const float* __restrict__ Wd,
                   const float* __restrict__ bias, unsigned short* __restrict__ Y)
{
    __shared__ unsigned short tile[1024 * 8];
    __shared__ float wl[72];
    __shared__ float bb[8];
    const int t    = threadIdx.x;
    const int coct = blockIdx.x & 127;
    const int b    = blockIdx.x >> 7;
    const unsigned short* xp = X + ((size_t)(b * 128 + coct)) * NPIX * 8;
#pragma unroll
    for (int k = 0; k < 4; k++) {
        const int slot = t + k * 256;
        *(u16x8*)(&tile[slot * 8]) = *(const u16x8*)(xp + slot * 8);
    }
    if (t < 72) wl[t] = Wd[coct * 72 + t];
    if (t < 8)  bb[t] = bias[coct * 8 + t];
    __syncthreads();

    const int px0 = t * 4;
    const int h   = px0 >> 5;
    const int c0  = px0 & 31;

    float acc[8][4];
#pragma unroll
    for (int ch = 0; ch < 8; ch++)
#pragma unroll
        for (int j = 0; j < 4; j++) acc[ch][j] = bb[ch];

#pragma unroll
    for (int ky = 0; ky < 3; ky++) {
        const int rr = h + ky - 1;
        if (rr >= 0 && rr < 32) {
            u16x8 P[6];
#pragma unroll
            for (int m = 0; m < 6; m++) {
                const int col = c0 - 1 + m;
                const int colc = col < 0 ? 0 : (col > 31 ? 31 : col);
                u16x8 v = *(const u16x8*)(&tile[(rr * 32 + colc) * 8]);
                if (col < 0 || col > 31) v = zero8();
                P[m] = v;
            }
#pragma unroll
            for (int ch = 0; ch < 8; ch++) {
                float g[6];
#pragma unroll
                for (int m = 0; m < 6; m++) g[m] = bf2f(P[m][ch]);
#pragma unroll
                for (int j = 0; j < 4; j++)
#pragma unroll
                    for (int kx = 0; kx < 3; kx++)
                        acc[ch][j] = fmaf(g[j + kx], wl[ch * 9 + ky * 3 + kx], acc[ch][j]);
            }
        }
    }
    unsigned short* yp = Y + ((size_t)(b * 128 + coct)) * NPIX * 8 + (size_t)px0 * 8;
#pragma unroll
    for (int j = 0; j < 4; j++) {
        u16x8 o8;
#pragma unroll
        for (int ch = 0; ch < 8; ch++) {
            float v = acc[ch][j];
            v = v * fminf(fmaxf(v + 3.f, 0.f), 6.f) * (1.f / 6.f);
            o8[ch] = f2bf(v);
        }
        *(u16x8*)(yp + j * 8) = o8;
    }
}

// ---------------------------------------------------------------------------
// Grouped 32->32 1x1 (24 groups), in-place on bf16 [c][n] D.
// ---------------------------------------------------------------------------
__global__ __launch_bounds__(256)
void grouped_pw(unsigned short* __restrict__ D, const float* __restrict__ Wg)
{
    __shared__ float ws[1024];
    const int t     = threadIdx.x;
    const int blk   = blockIdx.x;          // (b*24+g)*4 + chunk
    const int chunk = blk & 3;
    const int bg    = blk >> 2;
    const int g     = bg % 24;
    const int b     = bg / 24;
    for (int i = t; i < 1024; i += 256) ws[i] = Wg[g * 1024 + i];
    __syncthreads();
    const int px = chunk * 256 + t;
    unsigned short* dp = D + ((size_t)(b * 768 + g * 32)) * NPIX + px;
    float in[32];
#pragma unroll
    for (int i = 0; i < 32; i++) in[i] = bf2f(dp[(size_t)i * NPIX]);
#pragma unroll
    for (int o = 0; o < 32; o++) {
        float s = 0.f;
#pragma unroll
        for (int i = 0; i < 32; i++) s = fmaf(ws[o * 32 + i], in[i], s);
        dp[(size_t)o * NPIX] = f2bf(s);
    }
}

// ---------------------------------------------------------------------------
// Attention kv via MFMA: one block per (b,h), 4 waves each over a 256-px
// n-chunk. Fragments loaded directly from global; final kv[33][32] to kvp.
// ---------------------------------------------------------------------------
__global__ __launch_bounds__(256)
void attn_kv_mfma(const unsigned short* __restrict__ qkv,
                  const unsigned short* __restrict__ dpw,
                  float* __restrict__ kvp)
{
    __shared__ float kvred[4][33 * 33];   // [wave][d*33+e], stride 33 pads banks
    const int t    = threadIdx.x;
    const int lane = t & 63;
    const int w    = t >> 6;
    const int bh   = blockIdx.x;
    const int b    = bh >> 4;
    const int h    = bh & 15;

    const unsigned short* base = (h < 8)
        ? qkv + ((size_t)(b * 768 + h * 96)) * NPIX
        : dpw + ((size_t)(b * 768 + (h - 8) * 96)) * NPIX;
    const unsigned short* kp = base + 32 * NPIX;
    const unsigned short* vp = base + 64 * NPIX;

    const int l16 = lane & 15;
    const int ko  = (lane >> 4) * 8;     // k-oct within the 32-wide step
    const int nb  = w * 256;

    f32x4 acc[3][2];
#pragma unroll
    for (int i = 0; i < 3; i++)
#pragma unroll
        for (int j = 0; j < 2; j++) {
            f32x4 z = {0.f, 0.f, 0.f, 0.f};
            acc[i][j] = z;
        }

    // constant ones-fragment: A-row 32 (d=32) is all-ones, rows 33..47 zero
    bf16x8 ones;
#pragma unroll
    for (int j = 0; j < 8; j++) ones[j] = (l16 == 0) ? (short)0x3F80 : (short)0;

#pragma unroll
    for (int s = 0; s < 8; s++) {
        const int n0 = nb + s * 32 + ko;
        const bf16x8 av0 = *(const bf16x8*)(vp + (size_t)l16 * NPIX + n0);
        const bf16x8 av1 = *(const bf16x8*)(vp + (size_t)(16 + l16) * NPIX + n0);
        const u16x8 k0 = *(const u16x8*)(kp + (size_t)l16 * NPIX + n0);
        const u16x8 k1 = *(const u16x8*)(kp + (size_t)(16 + l16) * NPIX + n0);
        bf16x8 bk0, bk1;
#pragma unroll
        for (int j = 0; j < 8; j++) {
            bk0[j] = (k0[j] & 0x8000u) ? (short)0 : (short)k0[j];   // relu (exact on bf16)
            bk1[j] = (k1[j] & 0x8000u) ? (short)0 : (short)k1[j];
        }
        acc[0][0] = __builtin_amdgcn_mfma_f32_16x16x32_bf16(av0,  bk0, acc[0][0], 0, 0, 0);
        acc[0][1] = __builtin_amdgcn_mfma_f32_16x16x32_bf16(av0,  bk1, acc[0][1], 0, 0, 0);
        acc[1][0] = __builtin_amdgcn_mfma_f32_16x16x32_bf16(av1,  bk0, acc[1][0], 0, 0, 0);
        acc[1][1] = __builtin_amdgcn_mfma_f32_16x16x32_bf16(av1,  bk1, acc[1][1], 0, 0, 0);
        acc[2][0] = __builtin_amdgcn_mfma_f32_16x16x32_bf16(ones, bk0, acc[2][0], 0, 0, 0);
        acc[2][1] = __builtin_amdgcn_mfma_f32_16x16x32_bf16(ones, bk1, acc[2][1], 0, 0, 0);
    }

    // write partials. C/D: row d = dt*16 + (lane>>4)*4 + r, col e = et*16 + l16
    const int rbase = (lane >> 4) * 4;
#pragma unroll
    for (int dt = 0; dt < 2; dt++)
#pragma unroll
        for (int et = 0; et < 2; et++)
#pragma unroll
            for (int r = 0; r < 4; r++)
                kvred[w][(dt * 16 + rbase + r) * 33 + et * 16 + l16] = acc[dt][et][r];
    if (rbase == 0) {               // d == 32 only (lanes 0..15, reg 0)
#pragma unroll
        for (int et = 0; et < 2; et++)
            kvred[w][32 * 33 + et * 16 + l16] = acc[2][et][0];
    }
    __syncthreads();

#pragma unroll
    for (int k = 0; k < 5; k++) {
        const int idx = t + k * 256;
        if (idx < 1056) {
            const int d = idx >> 5;
            const int e = idx & 31;
            const int a = d * 33 + e;
            kvp[(size_t)bh * 1056 + idx] =
                kvred[0][a] + kvred[1][a] + kvred[2][a] + kvred[3][a];
        }
    }
}

// ---------------------------------------------------------------------------
// Attention phase 2: load final kv, apply; OUT = blocked bf16
// att_t[b][64][1024][8]  (c = h*32 + db*8 + j)
// v3: 1 pixel/thread (grid 1024 -> 16 waves/CU) AND ds_read_b128 kv reads.
// FIX vs R9: kvs preload covers all 264 float4s (strided loop), including
// the denominator row kvs[1024..1055].
// ---------------------------------------------------------------------------
__global__ __launch_bounds__(256)
void attn_apply(const unsigned short* __restrict__ qkv,
                const unsigned short* __restrict__ dpw,
                const float* __restrict__ kvp, unsigned short* __restrict__ att)
{
    __shared__ float kvs[1056];
    const int t   = threadIdx.x;
    const int blk = blockIdx.x;           // bh*4 + qc
    const int qc  = blk & 3;
    const int bh  = blk >> 2;
    const int b   = bh >> 4;
    const int h   = bh & 15;
    for (int i = t; i < 264; i += 256)
        *(f32x4*)(&kvs[i * 4]) = *(const f32x4*)(kvp + (size_t)bh * 1056 + i * 4);
    __syncthreads();
    const unsigned short* qp = (h < 8)
        ? qkv + ((size_t)(b * 768 + h * 96)) * NPIX
        : dpw + ((size_t)(b * 768 + (h - 8) * 96)) * NPIX;
    const int n = qc * 256 + t;

    float q[32];
#pragma unroll
    for (int e = 0; e < 32; e++) q[e] = fmaxf(bf2f(qp[(size_t)e * NPIX + n]), 0.f);

    float den = 0.f;
#pragma unroll
    for (int eq = 0; eq < 8; eq++) {
        const f32x4 kvv = *(const f32x4*)(&kvs[1024 + eq * 4]);
#pragma unroll
        for (int j = 0; j < 4; j++)
            den = fmaf(kvv[j], q[eq * 4 + j], den);
    }
    const float inv = 1.f / (den + 1e-15f);

#pragma unroll
    for (int db = 0; db < 4; db++) {
        u16x8 o8;
#pragma unroll
        for (int jj = 0; jj < 8; jj++) {
            const int d = db * 8 + jj;
            float a = 0.f;
#pragma unroll
            for (int eq = 0; eq < 8; eq++) {
                const f32x4 kvv = *(const f32x4*)(&kvs[d * 32 + eq * 4]);
#pragma unroll
                for (int j = 0; j < 4; j++)
                    a = fmaf(kvv[j], q[eq * 4 + j], a);
            }
            o8[jj] = f2bf(a * inv);
        }
        *(u16x8*)(att + (((size_t)(b * 64 + h * 4 + db)) * NPIX + n) * 8) = o8;
    }
}

// ---------------------------------------------------------------------------
extern "C" void kernel_launch(void* const* d_in, const int* in_sizes, int n_in,
                              void* d_out, int out_size, void* d_ws, size_t ws_size,
                              hipStream_t stream)
{
    (void)in_sizes; (void)n_in; (void)out_size; (void)ws_size;

    const float* x      = (const float*)d_in[0];
    const float* y      = (const float*)d_in[1];
    const float* qkv_w  = (const float*)d_in[2];
    const float* dw5_w  = (const float*)d_in[3];
    const float* pwg_w  = (const float*)d_in[4];
    const float* proj_w = (const float*)d_in[5];
    const float* proj_g = (const float*)d_in[6];
    const float* proj_b = (const float*)d_in[7];
    const float* proj_m = (const float*)d_in[8];
    const float* proj_v = (const float*)d_in[9];
    const float* inv_w  = (const float*)d_in[10];
    const float* inv_b  = (const float*)d_in[11];
    const float* dwc_w  = (const float*)d_in[12];
    const float* dwc_b  = (const float*)d_in[13];
    const float* pw_w   = (const float*)d_in[14];
    const float* pw_g   = (const float*)d_in[15];
    const float* pw_b   = (const float*)d_in[16];
    const float* pw_m   = (const float*)d_in[17];
    const float* pw_v   = (const float*)d_in[18];

    float* ws = (float*)d_ws;
    unsigned short* wqkv_b  = (unsigned short*)(ws + WQKV_OFF);
    unsigned short* wproj_b = (unsigned short*)(ws + WPROJ_OFF);
    unsigned short* winv_b  = (unsigned short*)(ws + WINV_OFF);
    unsigned short* wpw_b   = (unsigned short*)(ws + WPW_OFF);
    unsigned short* wxt     = (unsigned short*)(ws + XT_OFF);
    unsigned short* wqkv    = (unsigned short*)(ws + QKV_OFF);
    unsigned short* wdpw    = (unsigned short*)(ws + DPW_OFF);
    unsigned short* watt    = (unsigned short*)(ws + ATT_OFF);
    float*          wkvp    = ws + KVP_OFF;
    float*          wt1     = ws + T1_OFF;
    unsigned short* wt1t    = (unsigned short*)(ws + T1T_OFF);
    unsigned short* wh1t    = (unsigned short*)(ws + H1T_OFF);
    unsigned short* wh2t    = (unsigned short*)(ws + H2T_OFF);
    float* out = (float*)d_out;

    // weights -> blocked bf16 (once per launch)
    wconv<<<dim3(96),  256, 0, stream>>>(qkv_w,  wqkv_b,  768, 256);
    wconv<<<dim3(64),  256, 0, stream>>>(proj_w, wproj_b, 256, 512);
    wconv<<<dim3(128), 256, 0, stream>>>(inv_w,  winv_b,  1024, 256);
    wconv<<<dim3(128), 256, 0, stream>>>(pw_w,   wpw_b,   256, 1024);

    for (int blk = 0; blk < 2; blk++) {
        const float* t = (blk == 0) ? x : y;

        // --- lite_mla ---
        xpose_f32_bf16<<<dim3(2048), 256, 0, stream>>>(t, wxt, 256);
        gemm_blk<128, 0, false, 1><<<dim3(6, 128), 256, 0, stream>>>(
            wxt, wqkv_b, nullptr, wqkv, 768, 256,
            nullptr, nullptr, nullptr, nullptr, nullptr, nullptr);
        dwconv5x5_v3<<<dim3(6144), 256, 0, stream>>>(wqkv, dw5_w, wdpw);
        grouped_pw<<<dim3(1536), 256, 0, stream>>>(wdpw, pwg_w);
        attn_kv_mfma<<<dim3(256), 256, 0, stream>>>(wqkv, wdpw, wkvp);
        attn_apply<<<dim3(1024), 256, 0, stream>>>(wqkv, wdpw, wkvp, watt);
        gemm_blk<64, 1, false, 3><<<dim3(4, 128), 256, 0, stream>>>(
            watt, wproj_b, wt1, wt1t, 256, 512,
            t, proj_g, proj_b, proj_m, proj_v, nullptr);

        // --- mbconv ---
        gemm_blk<128, 2, false, 2><<<dim3(8, 128), 256, 0, stream>>>(
            wt1t, winv_b, nullptr, wh1t, 1024, 256,
            nullptr, nullptr, nullptr, nullptr, nullptr, inv_b);
        dwconv3x3_blk<<<dim3(2048), 256, 0, stream>>>(wh1t, dwc_w, dwc_b, wh2t);
        if (blk == 0) {
            gemm_blk<64, 1, false, 0><<<dim3(4, 128), 256, 0, stream>>>(
                wh2t, wpw_b, out, nullptr, 256, 1024,
                wt1, pw_g, pw_b, pw_m, pw_v, nullptr);
        } else {
            gemm_blk<64, 1, true, 0><<<dim3(4, 128), 256, 0, stream>>>(
                wh2t, wpw_b, out, nullptr, 256, 1024,
                wt1, pw_g, pw_b, pw_m, pw_v, nullptr);
        }
    }
}